// Round 17
// baseline (205.539 us; speedup 1.0000x reference)
//
#include <hip/hip_runtime.h>
#include <hip/hip_bf16.h>

typedef __attribute__((ext_vector_type(8))) short bf16x8;
typedef __attribute__((ext_vector_type(4))) short bf16x4;
typedef __attribute__((ext_vector_type(4))) float f32x4;

constexpr int NT   = 512;   // tiles
constexpr int NP   = 512;   // points (M)
constexpr int DIN  = 256;   // K
constexpr int DOUT = 256;   // N

__device__ __forceinline__ short f2bf(float f) {
  __hip_bfloat16 h = __float2bfloat16(f);
  return __builtin_bit_cast(short, h);
}

__device__ __forceinline__ bf16x8 cvt8(f32x4 a, f32x4 b) {
  bf16x8 r;
  r[0] = f2bf(a[0]); r[1] = f2bf(a[1]); r[2] = f2bf(a[2]); r[3] = f2bf(a[3]);
  r[4] = f2bf(b[0]); r[5] = f2bf(b[1]); r[6] = f2bf(b[2]); r[7] = f2bf(b[3]);
  return r;
}

// Ws: [n=256][k=256] bf16, 128 KB. Granule = 8 elem (16 B).
// g(n) = (n ^ (n>>2)) & 7: B-frag reads (16 consecutive n, fixed k) are
// 2-way (free); transpose staging writes 8-way.
__device__ __forceinline__ int wsw(int n, int k) {
  return n * DIN + (k ^ (((n ^ (n >> 2)) & 7) << 3));
}

__global__ __launch_bounds__(512, 2) void adaptive_linear_v9(
    const float* __restrict__ x,     // [NT][NP][DIN]
    const int*   __restrict__ idx,   // [NT]
    const float* __restrict__ w,     // [CH][DIN][DOUT]
    const float* __restrict__ bias,  // [DOUT]
    float*       __restrict__ out)   // [NT][NP][DOUT]
{
  __shared__ short Ws[DOUT * DIN];   // 128 KB; x never touches LDS

  const int tid = threadIdx.x;
  const int t   = blockIdx.x;

  const int c = idx[t];
  const float* xb = x   + (size_t)t * NP * DIN;
  const float* wb = w   + (size_t)c * DIN * DOUT;
  float*       ob = out + (size_t)t * NP * DOUT;

  // ---- W staging (all 8 waves, prologue only; v8-proven) ----------------
  {
    const int wl = tid & 63;
    const int wv = tid >> 6;
    f32x4 wr[8];
    #pragma unroll 1
    for (int ss = 0; ss < 4; ++ss) {
      const float* ws = wb + (size_t)(ss * 64 + wv * 8) * DOUT + wl * 4;
      #pragma unroll
      for (int q = 0; q < 8; ++q)
        wr[q] = *reinterpret_cast<const f32x4*>(ws + (size_t)q * DOUT);
      #pragma unroll
      for (int h = 0; h < 2; ++h) {
        const int k0 = ss * 64 + wv * 8 + h * 4;
        #pragma unroll
        for (int j = 0; j < 4; ++j) {
          bf16x4 v = { f2bf(wr[h*4+0][j]), f2bf(wr[h*4+1][j]),
                       f2bf(wr[h*4+2][j]), f2bf(wr[h*4+3][j]) };
          *reinterpret_cast<bf16x4*>(&Ws[wsw(wl * 4 + j, k0)]) = v;
        }
      }
    }
  }
  __syncthreads();                   // the ONLY barrier in the kernel

  // ---- self-paced waves: wid owns a 32-row strip per half ---------------
  const int l    = tid & 63;
  const int wid  = tid >> 6;         // 0..7
  const int lrow = l & 15;
  const int lk   = l >> 4;           // 0..3

  #pragma unroll 1
  for (int half = 0; half < 2; ++half) {
    const int rows = half * 256 + wid * 32;
    const float* xs0 = xb + (size_t)rows * DIN;

    f32x4 acc[2][16];
    #pragma unroll
    for (int fm = 0; fm < 2; ++fm)
      #pragma unroll
      for (int fn = 0; fn < 16; ++fn)
        acc[fm][fn] = f32x4{0.f, 0.f, 0.f, 0.f};

    // 3-deep A prefetch pipeline; all indices static (full unroll)
    f32x4 ar[3][2][2];
    #define LOADA(KS, BUF)                                                   \
      {                                                                      \
        const float* p0 = xs0 + (size_t)lrow * DIN + (KS) * 32 + lk * 8;     \
        _Pragma("unroll")                                                    \
        for (int fm = 0; fm < 2; ++fm) {                                     \
          const float* p = p0 + (size_t)fm * 16 * DIN;                       \
          ar[BUF][fm][0] = *reinterpret_cast<const f32x4*>(p);               \
          ar[BUF][fm][1] = *reinterpret_cast<const f32x4*>(p + 4);           \
        }                                                                    \
      }

    LOADA(0, 0)
    LOADA(1, 1)

    #pragma unroll
    for (int ks = 0; ks < 8; ++ks) {
      if (ks < 6) LOADA(ks + 2, (ks + 2) % 3)

      bf16x8 a[2];
      #pragma unroll
      for (int fm = 0; fm < 2; ++fm)
        a[fm] = cvt8(ar[ks % 3][fm][0], ar[ks % 3][fm][1]);

      const int kb = ks * 32 + lk * 8;
      __builtin_amdgcn_s_setprio(1);
      #pragma unroll
      for (int g = 0; g < 4; ++g) {      // 4 groups of 4 n-frags
        bf16x8 b[4];
        #pragma unroll
        for (int j = 0; j < 4; ++j)
          b[j] = *reinterpret_cast<const bf16x8*>(
              &Ws[wsw((g * 4 + j) * 16 + lrow, kb)]);
        #pragma unroll
        for (int fm = 0; fm < 2; ++fm)
          #pragma unroll
          for (int j = 0; j < 4; ++j)
            acc[fm][g * 4 + j] = __builtin_amdgcn_mfma_f32_16x16x32_bf16(
                a[fm], b[j], acc[fm][g * 4 + j], 0, 0, 0);
      }
      __builtin_amdgcn_s_setprio(0);
    }
    #undef LOADA

    // ---- epilogue: bias + plain f32 stores ------------------------------
    #pragma unroll
    for (int fm = 0; fm < 2; ++fm) {
      const int r0w = rows + fm * 16 + lk * 4;
      #pragma unroll
      for (int fn = 0; fn < 16; ++fn) {
        const int col = fn * 16 + lrow;
        const float bv = bias[col];
        float* op = ob + (size_t)r0w * DOUT + col;
        #pragma unroll
        for (int rr = 0; rr < 4; ++rr)
          op[(size_t)rr * DOUT] = acc[fm][fn][rr] + bv;
      }
    }
  }
}

extern "C" void kernel_launch(void* const* d_in, const int* in_sizes, int n_in,
                              void* d_out, int out_size, void* d_ws, size_t ws_size,
                              hipStream_t stream) {
  const float* x    = (const float*)d_in[0];
  const int*   idx  = (const int*)d_in[1];
  const float* w    = (const float*)d_in[2];
  const float* bias = (const float*)d_in[3];
  float* out = (float*)d_out;

  adaptive_linear_v9<<<NT, 512, 0, stream>>>(x, idx, w, bias, out);
}